// Round 4
// baseline (2403.378 us; speedup 1.0000x reference)
//
#include <hip/hip_runtime.h>
#include <stdint.h>

typedef __attribute__((ext_vector_type(4))) float f32x4;

#define T_WIN 4
#define BSZ   128
#define SSZ   64
#define DDIM  3136
#define FDIM  512
#define HDIM  512
#define LDIM  18
#define ROWS  8192   // B*S
#define KB    16

// ============================================================================
// fp32 SGEMM pass over one OpenBLAS K-chunk [ks,ke):
//   FIRST=1:  C  = chunk_sum            (ascending-k single-acc fma chain)
//   FIRST=0:  C  = __fadd_rn(C, chunk)  (sequential chunk adds, stream order)
// Bitwise-identical to the validated R3 chain-of-chains (np/OpenBLAS model).
// Block: 128x128 tile, 128 threads, 16x8 outputs/thread (single acc set).
// LDS: sA[16][256] k-major (A frags broadcast, 2-way free),
//      sB[16][132] with B frag split tx*4 / 64+tx*4 (2-way free).
// AMODE 0: A fp32;  AMODE 1: A uint8 (0/1 spikes -> exact products).
// ============================================================================
struct GArgs { const void* A; const float* B; float* C; int M; };

template<int AMODE, int FIRST>
__global__ __launch_bounds__(128, 2) void sgemm_pass(GArgs g0, GArgs g1, GArgs g2,
                                                     int N, int K, int ks, int ke) {
  GArgs g = g0;
  if (blockIdx.z == 1) g = g1;
  else if (blockIdx.z == 2) g = g2;
  const int m0 = blockIdx.x * 128;
  if (m0 >= g.M) return;              // uniform early-exit (small z-packed GEMMs)
  const int n0 = blockIdx.y * 128;

  __shared__ float sA[KB][256];       // [k][m]; stride 256: reads/writes 2-way (free)
  __shared__ float sB[KB][132];       // [k][n]

  const int tid = threadIdx.x;
  const int tx = tid & 15;            // n: cols tx*4..+3 and 64+tx*4..+3
  const int ty = tid >> 4;            // m: rows ty*16..+15

  const int am = tid;                 // A stage: one row per thread
  const int br = tid >> 3;            // B stage row 0..15
  const int bc = (tid & 7) * 16;      // B stage col chunk

  const float*   Af = (const float*)g.A;
  const uint8_t* A8 = (const uint8_t*)g.A;

  float acc[16][8];
#pragma unroll
  for (int i = 0; i < 16; i++)
#pragma unroll
    for (int j = 0; j < 8; j++) acc[i][j] = 0.f;

  for (int k0 = ks; k0 < ke; k0 += KB) {
    // ---- global -> regs ----
    f32x4 av[4];
    if (AMODE == 0) {
      const float* ap = Af + (size_t)(m0 + am) * K + k0;
#pragma unroll
      for (int c = 0; c < 4; c++) av[c] = *(const f32x4*)(ap + 4 * c);
    } else {
      uint4 wrd = *(const uint4*)(A8 + (size_t)(m0 + am) * K + k0);
      uint32_t u[4] = {wrd.x, wrd.y, wrd.z, wrd.w};
#pragma unroll
      for (int c = 0; c < 4; c++) {
        av[c][0] = (float)(u[c] & 255u);
        av[c][1] = (float)((u[c] >> 8) & 255u);
        av[c][2] = (float)((u[c] >> 16) & 255u);
        av[c][3] = (float)((u[c] >> 24) & 255u);
      }
    }
    f32x4 bv[4];
    const float* bp = g.B + (size_t)(k0 + br) * N + n0 + bc;
#pragma unroll
    for (int c = 0; c < 4; c++) bv[c] = *(const f32x4*)(bp + 4 * c);

    __syncthreads();                  // previous iter's LDS reads done
#pragma unroll
    for (int c = 0; c < 4; c++)
#pragma unroll
      for (int j = 0; j < 4; j++)
        sA[4 * c + j][am] = av[c][j];
#pragma unroll
    for (int c = 0; c < 4; c++)
      *(f32x4*)&sB[br][bc + 4 * c] = bv[c];
    __syncthreads();                  // tile ready

    // ---- inner k (ascending, single accumulator per output) ----
#pragma unroll 2
    for (int k = 0; k < KB; k++) {
      f32x4 a0 = *(const f32x4*)&sA[k][ty * 16];
      f32x4 a1 = *(const f32x4*)&sA[k][ty * 16 + 4];
      f32x4 a2 = *(const f32x4*)&sA[k][ty * 16 + 8];
      f32x4 a3 = *(const f32x4*)&sA[k][ty * 16 + 12];
      f32x4 b0 = *(const f32x4*)&sB[k][tx * 4];
      f32x4 b1 = *(const f32x4*)&sB[k][64 + tx * 4];
      float a[16] = {a0[0], a0[1], a0[2], a0[3], a1[0], a1[1], a1[2], a1[3],
                     a2[0], a2[1], a2[2], a2[3], a3[0], a3[1], a3[2], a3[3]};
      float b[8]  = {b0[0], b0[1], b0[2], b0[3], b1[0], b1[1], b1[2], b1[3]};
#pragma unroll
      for (int i = 0; i < 16; i++)
#pragma unroll
        for (int j = 0; j < 8; j++)
          acc[i][j] = __fmaf_rn(a[i], b[j], acc[i][j]);
    }
  }

  // ---- epilogue: write (FIRST) or sequential chunk add (RMW) ----
#pragma unroll
  for (int i = 0; i < 16; i++) {
    float* cp = g.C + (size_t)(m0 + ty * 16 + i) * N + n0;
    f32x4 v0 = {acc[i][0], acc[i][1], acc[i][2], acc[i][3]};
    f32x4 v1 = {acc[i][4], acc[i][5], acc[i][6], acc[i][7]};
    if (FIRST) {
      *(f32x4*)(cp + tx * 4) = v0;
      *(f32x4*)(cp + 64 + tx * 4) = v1;
    } else {
      f32x4 o0 = *(const f32x4*)(cp + tx * 4);
      f32x4 o1 = *(const f32x4*)(cp + 64 + tx * 4);
#pragma unroll
      for (int c = 0; c < 4; c++) { v0[c] = __fadd_rn(o0[c], v0[c]); v1[c] = __fadd_rn(o1[c], v1[c]); }
      *(f32x4*)(cp + tx * 4) = v0;
      *(f32x4*)(cp + 64 + tx * 4) = v1;
    }
  }
}

// ============================================================================
// p/t leaky filters: post-update states P[t,b,f], Tf[t,b,f]; exact np op order.
// ============================================================================
__global__ __launch_bounds__(256) void filter_pt_kernel(const float* __restrict__ prox,
                                                        const float* __restrict__ trunk,
                                                        float* __restrict__ P,
                                                        float* __restrict__ Tf) {
  int idx = blockIdx.x * 256 + threadIdx.x;   // 16384: (b, f/4)
  int b = idx >> 7;
  int fc = (idx & 127) << 2;
  f32x4 p = {0.f, 0.f, 0.f, 0.f}, t = {0.f, 0.f, 0.f, 0.f};
  for (int tt = 0; tt < T_WIN; tt++) {
    size_t o = (size_t)(tt * BSZ + b) * FDIM + fc;
    f32x4 x = *(const f32x4*)&prox[o];
    f32x4 y = *(const f32x4*)&trunk[o];
#pragma unroll
    for (int c = 0; c < 4; c++) {
      p[c] = __fadd_rn(p[c], __fmul_rn(__fsub_rn(x[c], p[c]), 0.5f));
      t[c] = __fadd_rn(t[c], __fmul_rn(__fsub_rn(y[c], t[c]), 0.5f));
    }
    *(f32x4*)&P[o] = p;
    *(f32x4*)&Tf[o] = t;
  }
}

// ============================================================================
// soma LIF chain -> spike bytes (0/1) for all t; exact np op order (no fma
// contraction of p*d + t).
// ============================================================================
__global__ __launch_bounds__(256) void lif_soma_kernel(const float* __restrict__ dist,
                                                       const float* __restrict__ P,
                                                       const float* __restrict__ Tf,
                                                       uint8_t* __restrict__ emb) {
  int idx = blockIdx.x * 256 + threadIdx.x;   // 1,048,576: (r, f/4)
  int r = idx >> 7;
  int fc = (idx & 127) << 2;
  int b = r >> 6;
  f32x4 d = {0.f, 0.f, 0.f, 0.f}, soma = {0.f, 0.f, 0.f, 0.f};
#pragma unroll
  for (int t = 0; t < T_WIN; t++) {
    f32x4 x  = *(const f32x4*)&dist[(size_t)(t * ROWS + r) * FDIM + fc];
    f32x4 pv = *(const f32x4*)&P[(size_t)(t * BSZ + b) * FDIM + fc];
    f32x4 tv = *(const f32x4*)&Tf[(size_t)(t * BSZ + b) * FDIM + fc];
    uint32_t bits = 0;
#pragma unroll
    for (int c = 0; c < 4; c++) {
      d[c] = __fadd_rn(d[c], __fmul_rn(__fsub_rn(x[c], d[c]), 0.5f));
      float pd = __fmul_rn(pv[c], d[c]);          // p*d (must NOT contract)
      float u  = __fadd_rn(pd, tv[c]);            // + t
      float w  = __fsub_rn(u, soma[c]);           // - soma
      soma[c] = __fadd_rn(soma[c], __fmul_rn(w, 0.5f));
      if (soma[c] >= 0.5f) { bits |= (1u << (8 * c)); soma[c] = 0.f; }
    }
    *(uint32_t*)&emb[(size_t)(t * ROWS + r) * FDIM + fc] = bits;
  }
}

// ============================================================================
// hidden LIF chain -> spike counts (u8, 0..4); exact op order; b1 added first.
// ============================================================================
__global__ __launch_bounds__(256) void lif_hidden_kernel(const float* __restrict__ H,
                                                         const float* __restrict__ b1,
                                                         uint8_t* __restrict__ cnt) {
  int idx = blockIdx.x * 256 + threadIdx.x;   // (r, f/4)
  int r = idx >> 7;
  int fc = (idx & 127) << 2;
  f32x4 bb = *(const f32x4*)&b1[fc];
  f32x4 lif = {0.f, 0.f, 0.f, 0.f};
  uint32_t counts = 0;
#pragma unroll
  for (int t = 0; t < T_WIN; t++) {
    f32x4 h = *(const f32x4*)&H[(size_t)(t * ROWS + r) * FDIM + fc];
#pragma unroll
    for (int c = 0; c < 4; c++) {
      float hv = __fadd_rn(h[c], bb[c]);
      lif[c] = __fadd_rn(lif[c], __fmul_rn(__fsub_rn(hv, lif[c]), 0.5f));
      if (lif[c] >= 0.5f) { counts += (1u << (8 * c)); lif[c] = 0.f; }
    }
  }
  *(uint32_t*)&cnt[(size_t)r * FDIM + fc] = counts;
}

// ============================================================================
// out[b,l,s] = sum_k (cnt[r,k]/4)*W2[k,l] + b2[l]; k ascending (uint4 groups,
// bytes in order), zero-skip bitwise exact. Writes final output directly.
// ============================================================================
__global__ __launch_bounds__(256) void out_kernel(const uint8_t* __restrict__ cnt,
                                                  const float* __restrict__ W2,
                                                  const float* __restrict__ b2,
                                                  float* __restrict__ out) {
  int idx = blockIdx.x * 256 + threadIdx.x;   // 147456 = 8192*18
  int r = idx / LDIM;
  int j = idx - r * LDIM;
  const uint4* crow = (const uint4*)(cnt + (size_t)r * HDIM);
  float acc = 0.f;
  for (int q = 0; q < HDIM / 16; q++) {
    uint4 wrd = crow[q];
    uint32_t u[4] = {wrd.x, wrd.y, wrd.z, wrd.w};
#pragma unroll
    for (int wq = 0; wq < 4; wq++)
#pragma unroll
      for (int s = 0; s < 4; s++) {
        uint32_t c = (u[wq] >> (8 * s)) & 255u;
        if (c) acc = __fmaf_rn((float)c * 0.25f, W2[(16 * q + 4 * wq + s) * LDIM + j], acc);
      }
  }
  int b = r >> 6, s = r & 63;
  out[(size_t)b * (LDIM * SSZ) + j * SSZ + s] = __fadd_rn(acc, b2[j]);
}

// ---------- workspace layout (88 MB) ----------
// dist_all / H_all fp32  @ 0          (67,108,864)
// emb8 u8                @ 67,108,864 (16,777,216)
// cnt8 u8                @ 83,886,080 ( 4,194,304)
// prox_raw fp32          @ 88,080,384 ( 1,048,576)
// trunk_raw fp32         @ 89,128,960 ( 1,048,576)
// P fp32                 @ 90,177,536 ( 1,048,576)
// Tf fp32                @ 91,226,112 ( 1,048,576)  -> total 92,274,688

extern "C" void kernel_launch(void* const* d_in, const int* in_sizes, int n_in,
                              void* d_out, int out_size, void* d_ws, size_t ws_size,
                              hipStream_t stream) {
  const float* se     = (const float*)d_in[0];
  const float* te     = (const float*)d_in[1];
  const float* ee     = (const float*)d_in[2];
  const float* Wprox  = (const float*)d_in[3];
  const float* Wdist  = (const float*)d_in[4];
  const float* Wtrunk = (const float*)d_in[5];
  const float* W1     = (const float*)d_in[6];
  const float* b1     = (const float*)d_in[7];
  const float* W2     = (const float*)d_in[8];
  const float* b2     = (const float*)d_in[9];

  char* ws = (char*)d_ws;
  float*   dist_all  = (float*)(ws);                 // later reused as H_all
  uint8_t* emb8      = (uint8_t*)(ws + 67108864);
  uint8_t* cnt8      = (uint8_t*)(ws + 83886080);
  float*   prox_raw  = (float*)(ws + 88080384);
  float*   trunk_raw = (float*)(ws + 89128960);
  float*   P         = (float*)(ws + 90177536);
  float*   Tf        = (float*)(ws + 91226112);

  // OpenBLAS K-chunk boundaries (GEMM_Q=384, tail halving) — validated in R3.
  static const int KC[10] = {0, 384, 768, 1152, 1536, 1920, 2304, 2688, 2912, 3136};

  // 1. batched input GEMMs, one launch per K-chunk (z=0: dist; z=1/2: prox/trunk)
  GArgs gd{te, Wdist, dist_all, T_WIN * ROWS};
  GArgs gp{se, Wprox, prox_raw, T_WIN * BSZ};
  GArgs gt{ee, Wtrunk, trunk_raw, T_WIN * BSZ};
  {
    dim3 gg(256, 4, 3), bb(128);
    sgemm_pass<0, 1><<<gg, bb, 0, stream>>>(gd, gp, gt, FDIM, DDIM, KC[0], KC[1]);
    for (int p = 1; p < 9; p++)
      sgemm_pass<0, 0><<<gg, bb, 0, stream>>>(gd, gp, gt, FDIM, DDIM, KC[p], KC[p + 1]);
  }

  // 2. p/t filters (exact chains)
  filter_pt_kernel<<<64, 256, 0, stream>>>(prox_raw, trunk_raw, P, Tf);

  // 3. soma LIF -> binary spikes (u8)
  lif_soma_kernel<<<4096, 256, 0, stream>>>(dist_all, P, Tf, emb8);

  // 4. H = emb @ W1, all t batched (overwrites dist_all, dead); chunks {256,256}
  GArgs gh{emb8, W1, dist_all, T_WIN * ROWS};
  {
    dim3 gg(256, 4, 1), bb(128);
    sgemm_pass<1, 1><<<gg, bb, 0, stream>>>(gh, gh, gh, HDIM, FDIM, 0, 256);
    sgemm_pass<1, 0><<<gg, bb, 0, stream>>>(gh, gh, gh, HDIM, FDIM, 256, 512);
  }

  // 5. hidden LIF -> spike counts
  lif_hidden_kernel<<<4096, 256, 0, stream>>>(dist_all, b1, cnt8);

  // 6. output GEMM + b2 + [B,LAST,S] transpose, fp32
  out_kernel<<<576, 256, 0, stream>>>(cnt8, W2, b2, (float*)d_out);
}

// Round 5
// 2115.663 us; speedup vs baseline: 1.1360x; 1.1360x over previous
//
#include <hip/hip_runtime.h>
#include <stdint.h>

typedef __attribute__((ext_vector_type(4))) float f32x4;

#define T_WIN 4
#define BSZ   128
#define SSZ   64
#define DDIM  3136
#define FDIM  512
#define HDIM  512
#define LDIM  18
#define ROWS  8192   // B*S
#define KB    16

// Per-gemm chunk-buffer stride = M*N floats; chunk q lives at C + q*M*N.
struct GArgs { const void* A; const float* B; float* C; int M; };

// OpenBLAS K-chunk bounds for K=3136 (GEMM_Q=384, tail halving) — validated R3/R4.
__device__ __forceinline__ void kchunk3136(int z, int& ks, int& ke) {
  ks = (z <= 7) ? 384 * z : 2912;
  ke = (z <= 6) ? 384 * (z + 1) : ((z == 7) ? 2912 : 3136);
}

// ============================================================================
// fp32 GEMM, all K-chunks in ONE launch (z = chunk): writes chunk partial sum
// (ascending-k single-accumulator fma chain from zero) to its own buffer.
// The in-order chunk adds happen in the consumer kernels (bitwise = RMW chain).
// Block: 128x128 tile, 128 threads, 16x8 outputs/thread, KB=16, global->reg
// prefetch so HBM latency hides under the 2048-FMA inner loop.
// SMALLS: blockIdx.x >= 256 handles the prox/trunk 512-row GEMMs (g1/g2).
// AMODE 0: A fp32;  AMODE 1: A uint8 (0/1 spikes -> exact products).
// ============================================================================
template<int AMODE, int SMALLS>
__global__ __launch_bounds__(128, 2) void gemm_chunks(GArgs g0, GArgs g1, GArgs g2,
                                                      int N, int K, int kcmode) {
  int xb = blockIdx.x;
  GArgs g = g0;
  if (SMALLS && xb >= 256) {
    int idx = xb - 256;
    g = (idx >> 2) ? g2 : g1;
    xb = idx & 3;
  }
  int ks, ke;
  if (kcmode == 0) kchunk3136(blockIdx.z, ks, ke);
  else { ks = blockIdx.z * 256; ke = ks + 256; }

  const int m0 = xb * 128;
  const int n0 = blockIdx.y * 128;
  float* C = g.C + (size_t)blockIdx.z * g.M * N;

  __shared__ float sA[KB][256];       // [k][m]; reads/writes <=2-way (free)
  __shared__ float sB[KB][132];

  const int tid = threadIdx.x;
  const int tx = tid & 15;            // n: cols tx*4..+3 and 64+tx*4..+3
  const int ty = tid >> 4;            // m: rows ty*16..+15

  const int am = tid;                 // A stage: one row per thread, 16 k-floats
  const int br = tid >> 3;            // B stage row 0..15
  const int bc = (tid & 7) * 16;      // B stage col chunk

  const float*   Af = (const float*)g.A;
  const uint8_t* A8 = (const uint8_t*)g.A;

  float acc[16][8];
#pragma unroll
  for (int i = 0; i < 16; i++)
#pragma unroll
    for (int j = 0; j < 8; j++) acc[i][j] = 0.f;

  // ---- prefetch registers ----
  f32x4 av[4], bv[4];
  auto load_step = [&](int k0) {
    if (AMODE == 0) {
      const float* ap = Af + (size_t)(m0 + am) * K + k0;
#pragma unroll
      for (int c = 0; c < 4; c++) av[c] = *(const f32x4*)(ap + 4 * c);
    } else {
      uint4 wrd = *(const uint4*)(A8 + (size_t)(m0 + am) * K + k0);
      uint32_t u[4] = {wrd.x, wrd.y, wrd.z, wrd.w};
#pragma unroll
      for (int c = 0; c < 4; c++) {
        av[c][0] = (float)(u[c] & 255u);
        av[c][1] = (float)((u[c] >> 8) & 255u);
        av[c][2] = (float)((u[c] >> 16) & 255u);
        av[c][3] = (float)((u[c] >> 24) & 255u);
      }
    }
    const float* bp = g.B + (size_t)(k0 + br) * N + n0 + bc;
#pragma unroll
    for (int c = 0; c < 4; c++) bv[c] = *(const f32x4*)(bp + 4 * c);
  };

  load_step(ks);
  for (int k0 = ks; k0 < ke; k0 += KB) {
    __syncthreads();                  // previous iter's LDS reads done
#pragma unroll
    for (int c = 0; c < 4; c++)
#pragma unroll
      for (int j = 0; j < 4; j++)
        sA[4 * c + j][am] = av[c][j];
#pragma unroll
    for (int c = 0; c < 4; c++)
      *(f32x4*)&sB[br][bc + 4 * c] = bv[c];
    __syncthreads();                  // tile ready

    if (k0 + KB < ke) load_step(k0 + KB);   // issue next loads; wait lands at next ds_write

    // ---- inner k (ascending, single accumulator per output) ----
#pragma unroll 4
    for (int k = 0; k < KB; k++) {
      f32x4 a0 = *(const f32x4*)&sA[k][ty * 16];
      f32x4 a1 = *(const f32x4*)&sA[k][ty * 16 + 4];
      f32x4 a2 = *(const f32x4*)&sA[k][ty * 16 + 8];
      f32x4 a3 = *(const f32x4*)&sA[k][ty * 16 + 12];
      f32x4 b0 = *(const f32x4*)&sB[k][tx * 4];
      f32x4 b1 = *(const f32x4*)&sB[k][64 + tx * 4];
      float a[16] = {a0[0], a0[1], a0[2], a0[3], a1[0], a1[1], a1[2], a1[3],
                     a2[0], a2[1], a2[2], a2[3], a3[0], a3[1], a3[2], a3[3]};
      float b[8]  = {b0[0], b0[1], b0[2], b0[3], b1[0], b1[1], b1[2], b1[3]};
#pragma unroll
      for (int i = 0; i < 16; i++)
#pragma unroll
        for (int j = 0; j < 8; j++)
          acc[i][j] = __fmaf_rn(a[i], b[j], acc[i][j]);
    }
  }

  // ---- store chunk partial sums ----
#pragma unroll
  for (int i = 0; i < 16; i++) {
    float* cp = C + (size_t)(m0 + ty * 16 + i) * N + n0;
    f32x4 v0 = {acc[i][0], acc[i][1], acc[i][2], acc[i][3]};
    f32x4 v1 = {acc[i][4], acc[i][5], acc[i][6], acc[i][7]};
    *(f32x4*)(cp + tx * 4) = v0;
    *(f32x4*)(cp + 64 + tx * 4) = v1;
  }
}

// ============================================================================
// p/t filters: in-order 9-chunk reduction (bitwise = sequential RMW adds),
// then exact np LIF chains. P/Tf are post-update states.
// ============================================================================
__global__ __launch_bounds__(256) void filter_pt9(const float* __restrict__ Cp,
                                                  const float* __restrict__ Ct,
                                                  float* __restrict__ P,
                                                  float* __restrict__ Tf) {
  const size_t CH = (size_t)T_WIN * BSZ * FDIM;   // 262144 floats
  int idx = blockIdx.x * 256 + threadIdx.x;   // 16384: (b, f/4)
  int b = idx >> 7;
  int fc = (idx & 127) << 2;
  f32x4 p = {0.f, 0.f, 0.f, 0.f}, t = {0.f, 0.f, 0.f, 0.f};
  for (int tt = 0; tt < T_WIN; tt++) {
    size_t o = (size_t)(tt * BSZ + b) * FDIM + fc;
    f32x4 x = *(const f32x4*)&Cp[o];
    f32x4 y = *(const f32x4*)&Ct[o];
    for (int q = 1; q < 9; q++) {
      f32x4 xq = *(const f32x4*)&Cp[o + q * CH];
      f32x4 yq = *(const f32x4*)&Ct[o + q * CH];
#pragma unroll
      for (int c = 0; c < 4; c++) { x[c] = __fadd_rn(x[c], xq[c]); y[c] = __fadd_rn(y[c], yq[c]); }
    }
#pragma unroll
    for (int c = 0; c < 4; c++) {
      p[c] = __fadd_rn(p[c], __fmul_rn(__fsub_rn(x[c], p[c]), 0.5f));
      t[c] = __fadd_rn(t[c], __fmul_rn(__fsub_rn(y[c], t[c]), 0.5f));
    }
    *(f32x4*)&P[o] = p;
    *(f32x4*)&Tf[o] = t;
  }
}

// ============================================================================
// soma LIF: in-order 9-chunk reduction of dist, then exact np chain -> spikes.
// ============================================================================
__global__ __launch_bounds__(256) void lif_soma9(const float* __restrict__ Cd,
                                                 const float* __restrict__ P,
                                                 const float* __restrict__ Tf,
                                                 uint8_t* __restrict__ emb) {
  const size_t CH = (size_t)T_WIN * ROWS * FDIM;  // 16,777,216 floats
  int idx = blockIdx.x * 256 + threadIdx.x;   // 1,048,576: (r, f/4)
  int r = idx >> 7;
  int fc = (idx & 127) << 2;
  int b = r >> 6;
  f32x4 d = {0.f, 0.f, 0.f, 0.f}, soma = {0.f, 0.f, 0.f, 0.f};
#pragma unroll
  for (int t = 0; t < T_WIN; t++) {
    size_t o = (size_t)(t * ROWS + r) * FDIM + fc;
    f32x4 x = *(const f32x4*)&Cd[o];
#pragma unroll
    for (int q = 1; q < 9; q++) {
      f32x4 xq = *(const f32x4*)&Cd[o + q * CH];
#pragma unroll
      for (int c = 0; c < 4; c++) x[c] = __fadd_rn(x[c], xq[c]);
    }
    f32x4 pv = *(const f32x4*)&P[(size_t)(t * BSZ + b) * FDIM + fc];
    f32x4 tv = *(const f32x4*)&Tf[(size_t)(t * BSZ + b) * FDIM + fc];
    uint32_t bits = 0;
#pragma unroll
    for (int c = 0; c < 4; c++) {
      d[c] = __fadd_rn(d[c], __fmul_rn(__fsub_rn(x[c], d[c]), 0.5f));
      float pd = __fmul_rn(pv[c], d[c]);          // p*d (must NOT contract)
      float u  = __fadd_rn(pd, tv[c]);            // + t
      float w  = __fsub_rn(u, soma[c]);           // - soma
      soma[c] = __fadd_rn(soma[c], __fmul_rn(w, 0.5f));
      if (soma[c] >= 0.5f) { bits |= (1u << (8 * c)); soma[c] = 0.f; }
    }
    *(uint32_t*)&emb[o] = bits;
  }
}

// ============================================================================
// hidden LIF: in-order 2-chunk reduction of H, +b1 first, exact chain -> counts.
// ============================================================================
__global__ __launch_bounds__(256) void lif_hidden2(const float* __restrict__ Hc,
                                                   const float* __restrict__ b1,
                                                   uint8_t* __restrict__ cnt) {
  const size_t CH = (size_t)T_WIN * ROWS * FDIM;
  int idx = blockIdx.x * 256 + threadIdx.x;   // (r, f/4)
  int r = idx >> 7;
  int fc = (idx & 127) << 2;
  f32x4 bb = *(const f32x4*)&b1[fc];
  f32x4 lif = {0.f, 0.f, 0.f, 0.f};
  uint32_t counts = 0;
#pragma unroll
  for (int t = 0; t < T_WIN; t++) {
    size_t o = (size_t)(t * ROWS + r) * FDIM + fc;
    f32x4 h0 = *(const f32x4*)&Hc[o];
    f32x4 h1 = *(const f32x4*)&Hc[o + CH];
#pragma unroll
    for (int c = 0; c < 4; c++) {
      float hv = __fadd_rn(__fadd_rn(h0[c], h1[c]), bb[c]);
      lif[c] = __fadd_rn(lif[c], __fmul_rn(__fsub_rn(hv, lif[c]), 0.5f));
      if (lif[c] >= 0.5f) { counts += (1u << (8 * c)); lif[c] = 0.f; }
    }
  }
  *(uint32_t*)&cnt[(size_t)r * FDIM + fc] = counts;
}

// ============================================================================
// out[b,l,s] = sum_k (cnt[r,k]/4)*W2[k,l] + b2[l]; k ascending, zero-skip
// bitwise exact (counts/4 are exact). Writes final output directly.
// ============================================================================
__global__ __launch_bounds__(256) void out_kernel(const uint8_t* __restrict__ cnt,
                                                  const float* __restrict__ W2,
                                                  const float* __restrict__ b2,
                                                  float* __restrict__ out) {
  int idx = blockIdx.x * 256 + threadIdx.x;   // 147456 = 8192*18
  int r = idx / LDIM;
  int j = idx - r * LDIM;
  const uint4* crow = (const uint4*)(cnt + (size_t)r * HDIM);
  float acc = 0.f;
  for (int q = 0; q < HDIM / 16; q++) {
    uint4 wrd = crow[q];
    uint32_t u[4] = {wrd.x, wrd.y, wrd.z, wrd.w};
#pragma unroll
    for (int wq = 0; wq < 4; wq++)
#pragma unroll
      for (int s = 0; s < 4; s++) {
        uint32_t c = (u[wq] >> (8 * s)) & 255u;
        if (c) acc = __fmaf_rn((float)c * 0.25f, W2[(16 * q + 4 * wq + s) * LDIM + j], acc);
      }
  }
  int b = r >> 6, s = r & 63;
  out[(size_t)b * (LDIM * SSZ) + j * SSZ + s] = __fadd_rn(acc, b2[j]);
}

// ---------- workspace layout (~616 MB; harness ws is ~1.6 GB per fill size) ----------
// Cd   9 x 64 MB  @ 0            (603,979,776)   dist chunk partial sums
//   (Hc 2 x 64 MB aliases Cd[0..1] — Cd dead once lif_soma9 completes)
// Cp   9 x 1 MB   @ 603,979,776  (  9,437,184)
// Ct   9 x 1 MB   @ 613,416,960  (  9,437,184)
// P    1 MB       @ 622,854,144
// Tf   1 MB       @ 623,902,720
// emb  16 MB      @ 624,951,296
// cnt  4 MB       @ 641,728,512   -> total 645,922,816

extern "C" void kernel_launch(void* const* d_in, const int* in_sizes, int n_in,
                              void* d_out, int out_size, void* d_ws, size_t ws_size,
                              hipStream_t stream) {
  const float* se     = (const float*)d_in[0];
  const float* te     = (const float*)d_in[1];
  const float* ee     = (const float*)d_in[2];
  const float* Wprox  = (const float*)d_in[3];
  const float* Wdist  = (const float*)d_in[4];
  const float* Wtrunk = (const float*)d_in[5];
  const float* W1     = (const float*)d_in[6];
  const float* b1     = (const float*)d_in[7];
  const float* W2     = (const float*)d_in[8];
  const float* b2     = (const float*)d_in[9];

  char* ws = (char*)d_ws;
  float*   Cd   = (float*)(ws);
  float*   Hc   = (float*)(ws);                 // aliases Cd[0..1] (dead by then)
  float*   Cp   = (float*)(ws + 603979776);
  float*   Ct   = (float*)(ws + 613416960);
  float*   P    = (float*)(ws + 622854144);
  float*   Tf   = (float*)(ws + 623902720);
  uint8_t* emb8 = (uint8_t*)(ws + 624951296);
  uint8_t* cnt8 = (uint8_t*)(ws + 641728512);

  // 1. ALL input-GEMM K-chunks in one launch (z = chunk 0..8;
  //    x<256: dist row-blocks; x=256..263: prox/trunk small GEMMs)
  GArgs gd{te, Wdist, Cd, T_WIN * ROWS};
  GArgs gp{se, Wprox, Cp, T_WIN * BSZ};
  GArgs gt{ee, Wtrunk, Ct, T_WIN * BSZ};
  gemm_chunks<0, 1><<<dim3(264, 4, 9), 128, 0, stream>>>(gd, gp, gt, FDIM, DDIM, 0);

  // 2. p/t filters (9-chunk in-order reduce + exact chains)
  filter_pt9<<<64, 256, 0, stream>>>(Cp, Ct, P, Tf);

  // 3. soma LIF (9-chunk in-order reduce + exact chains) -> binary spikes
  lif_soma9<<<4096, 256, 0, stream>>>(Cd, P, Tf, emb8);

  // 4. H = emb @ W1, both K-chunks {0..256,256..512} in one launch (over Cd, dead)
  GArgs gh{emb8, W1, Hc, T_WIN * ROWS};
  gemm_chunks<1, 0><<<dim3(256, 4, 2), 128, 0, stream>>>(gh, gh, gh, HDIM, FDIM, 1);

  // 5. hidden LIF (2-chunk in-order reduce) -> spike counts
  lif_hidden2<<<4096, 256, 0, stream>>>(Hc, b1, cnt8);

  // 6. output GEMM + b2 + [B,LAST,S] transpose, fp32
  out_kernel<<<576, 256, 0, stream>>>(cnt8, W2, b2, (float*)d_out);
}